// Round 1
// baseline (542.927 us; speedup 1.0000x reference)
//
#include <hip/hip_runtime.h>
#include <hip/hip_bf16.h>
#include <hip/hip_fp16.h>

#define B_  4
#define V_  256
#define H_  512
#define NH_ 8
#define HD_ 64
#define E_  32640   // V*(V-1)/2

typedef _Float16 half8 __attribute__((ext_vector_type(8)));
typedef float    f32x4 __attribute__((ext_vector_type(4)));

__device__ __forceinline__ float gelu_f(float x) {
    return 0.5f * x * (1.0f + erff(x * 0.70710678118654752f));
}

__device__ __forceinline__ float wred_add(float v) {
    #pragma unroll
    for (int off = 32; off > 0; off >>= 1) v += __shfl_xor(v, off, 64);
    return v;
}

// ---------------------------------------------------------------- prep kernels
__global__ void k_vproj(const float* __restrict__ verts, const float* __restrict__ wp,
                        const float* __restrict__ bp, float* __restrict__ x) {
    int t = blockIdx.x * 256 + threadIdx.x;          // < 1024*512
    int bv = t >> 9, hh = t & 511;
    const float* vr = verts + bv * 3;
    const float* wr = wp + hh * 3;
    x[t] = vr[0] * wr[0] + vr[1] * wr[1] + vr[2] * wr[2] + bp[hh];
}

__global__ void k_w2h(const float* __restrict__ w2, _Float16* __restrict__ w2h) {
    int t = blockIdx.x * 256 + threadIdx.x;          // < 256*512
    w2h[t] = (_Float16)w2[t];
}

__global__ void k_etab(int2* __restrict__ etab) {
    int t = blockIdx.x * 256 + threadIdx.x;
    if (t >= E_) return;
    double disc = (double)(2 * V_ - 1) * (2 * V_ - 1) - 8.0 * (double)t;
    int i = (int)((2 * V_ - 1 - sqrt(disc)) * 0.5);
    if (i < 0) i = 0;
    if (i > V_ - 2) i = V_ - 2;
    while (i < V_ - 2 && (i + 1) * (2 * V_ - 1 - (i + 1)) / 2 <= t) ++i;
    while (i > 0 && i * (2 * V_ - 1 - i) / 2 > t) --i;
    int j = t - i * (2 * V_ - 1 - i) / 2 + i + 1;
    etab[t] = make_int2(i, j);
}

// ---------------------------------------------------------------- fp32 GEMM
// C[M,N] = A[M,K] @ W[:, woff:woff+K]^T  (+bias) (+res), W row-major with ldw
__global__ __launch_bounds__(256) void k_gemm(
        const float* __restrict__ A, const float* __restrict__ W,
        const float* __restrict__ bias, const float* __restrict__ res,
        float* __restrict__ C, int M, int N, int K, int ldw, int woff)
{
    __shared__ float As[16][64];
    __shared__ float Ws[16][64];
    const int tid = threadIdx.x;
    const int ty = tid >> 4, tx = tid & 15;
    const int row0 = blockIdx.y * 64, col0 = blockIdx.x * 64;
    const int lrow = tid >> 2, lk = (tid & 3) * 4;
    float acc[4][4] = {};
    for (int kb = 0; kb < K; kb += 16) {
        f32x4 av = *(const f32x4*)(A + (size_t)(row0 + lrow) * K + kb + lk);
        f32x4 wv = *(const f32x4*)(W + (size_t)(col0 + lrow) * ldw + woff + kb + lk);
        __syncthreads();
        #pragma unroll
        for (int c = 0; c < 4; ++c) { As[lk + c][lrow] = av[c]; Ws[lk + c][lrow] = wv[c]; }
        __syncthreads();
        #pragma unroll
        for (int kk = 0; kk < 16; ++kk) {
            f32x4 a4 = *(const f32x4*)&As[kk][ty * 4];
            f32x4 w4 = *(const f32x4*)&Ws[kk][tx * 4];
            #pragma unroll
            for (int i = 0; i < 4; ++i)
                #pragma unroll
                for (int j = 0; j < 4; ++j) acc[i][j] += a4[i] * w4[j];
        }
    }
    #pragma unroll
    for (int i = 0; i < 4; ++i) {
        int r = row0 + ty * 4 + i;
        #pragma unroll
        for (int j = 0; j < 4; ++j) {
            int c = col0 + tx * 4 + j;
            float v = acc[i][j];
            if (bias) v += bias[c];
            if (res)  v += res[(size_t)r * N + c];
            C[(size_t)r * N + c] = v;
        }
    }
}

// ---------------------------------------------------------------- attention
// grid = B*NH*8 (8 query-groups of 32), 256 threads = 32 queries x 8 key-groups
__global__ __launch_bounds__(256) void k_attn(const float* __restrict__ qkv,
                                              float* __restrict__ ctx) {
    const int bid = blockIdx.x;
    const int qg = bid & 7, h = (bid >> 3) & 7, b = bid >> 6;
    const int tid = threadIdx.x;
    const int q = tid & 31, g = tid >> 5;
    const int qi = qg * 32 + q;
    const float* qrow = qkv + ((size_t)(b * V_ + qi)) * 1536 + h * 64;
    float qreg[64];
    #pragma unroll
    for (int dd = 0; dd < 16; ++dd) {
        f32x4 t4 = *(const f32x4*)(qrow + dd * 4);
        qreg[dd*4+0]=t4[0]; qreg[dd*4+1]=t4[1]; qreg[dd*4+2]=t4[2]; qreg[dd*4+3]=t4[3];
    }
    float m = -1e30f, lsum = 0.0f;
    float cacc[64];
    #pragma unroll
    for (int d = 0; d < 64; ++d) cacc[d] = 0.0f;
    for (int kk = 0; kk < 32; ++kk) {
        const int kr = g * 32 + kk;
        const float* krow = qkv + ((size_t)(b * V_ + kr)) * 1536 + 512 + h * 64;
        float s = 0.0f;
        #pragma unroll
        for (int dd = 0; dd < 16; ++dd) {
            f32x4 kv = *(const f32x4*)(krow + dd * 4);
            s += qreg[dd*4+0]*kv[0] + qreg[dd*4+1]*kv[1] + qreg[dd*4+2]*kv[2] + qreg[dd*4+3]*kv[3];
        }
        s *= 0.125f;
        float mn = fmaxf(m, s);
        float scale = __expf(m - mn);
        float p = __expf(s - mn);
        lsum = lsum * scale + p;
        const float* vrow = qkv + ((size_t)(b * V_ + kr)) * 1536 + 1024 + h * 64;
        #pragma unroll
        for (int dd = 0; dd < 16; ++dd) {
            f32x4 vv = *(const f32x4*)(vrow + dd * 4);
            #pragma unroll
            for (int c = 0; c < 4; ++c)
                cacc[dd*4+c] = cacc[dd*4+c] * scale + p * vv[c];
        }
        m = mn;
    }
    __shared__ float mls[8][32][2];
    __shared__ float cbuf[8][32][16];
    mls[g][q][0] = m; mls[g][q][1] = lsum;
    __syncthreads();
    float M = -1e30f;
    #pragma unroll
    for (int gg = 0; gg < 8; ++gg) M = fmaxf(M, mls[gg][q][0]);
    float L = 0.0f;
    #pragma unroll
    for (int gg = 0; gg < 8; ++gg) L += mls[gg][q][1] * __expf(mls[gg][q][0] - M);
    const float myscale = __expf(m - M) / L;
    for (int c = 0; c < 4; ++c) {
        #pragma unroll
        for (int d = 0; d < 16; ++d) cbuf[g][q][d] = cacc[c * 16 + d] * myscale;
        __syncthreads();
        for (int idx = tid; idx < 512; idx += 256) {
            int qq = idx >> 4, d = idx & 15;
            float sum = 0.0f;
            #pragma unroll
            for (int gg = 0; gg < 8; ++gg) sum += cbuf[gg][qq][d];
            ctx[((size_t)(b * V_ + qg * 32 + qq)) * 512 + h * 64 + c * 16 + d] = sum;
        }
        __syncthreads();
    }
}

// ---------------------------------------------------------------- fused edge MLP
// grid = B * 510 (64 edges per block), 256 threads = 4 waves, 64KB dynamic LDS
__global__ __launch_bounds__(256) void k_edge(
        const float* __restrict__ Am, const float* __restrict__ Bm,
        const _Float16* __restrict__ w2h,
        const float* __restrict__ g1, const float* __restrict__ be1,
        const float* __restrict__ b2, const float* __restrict__ g2,
        const float* __restrict__ be2, const float* __restrict__ w3,
        const float* __restrict__ b3, const int2* __restrict__ etab,
        float* __restrict__ out)
{
    extern __shared__ unsigned char smem[];   // 64KB: [64][512] f16 g  ->  [64][256] f32 h2
    const int tid = threadIdx.x;
    const int w = tid >> 6;
    const int l = tid & 63;
    const int b  = blockIdx.x / 510;
    const int eb = blockIdx.x % 510;

    // ---- Phase A: h1 = A[i]+Bv[j]; LN1; gelu; -> fp16 in LDS (XOR-swizzled)
    {
        const int d0 = l * 8;
        f32x4 g1a = *(const f32x4*)(g1 + d0);
        f32x4 g1b = *(const f32x4*)(g1 + d0 + 4);
        f32x4 e1a = *(const f32x4*)(be1 + d0);
        f32x4 e1b = *(const f32x4*)(be1 + d0 + 4);
        for (int el = 0; el < 16; ++el) {
            const int e = w * 16 + el;
            const int2 ij = etab[eb * 64 + e];
            const float* ar = Am + ((size_t)(b * V_ + ij.x)) * 512 + d0;
            const float* br = Bm + ((size_t)(b * V_ + ij.y)) * 512 + d0;
            f32x4 a0 = *(const f32x4*)ar, a1 = *(const f32x4*)(ar + 4);
            f32x4 c0 = *(const f32x4*)br, c1 = *(const f32x4*)(br + 4);
            f32x4 v0 = a0 + c0, v1 = a1 + c1;
            float s  = v0[0]+v0[1]+v0[2]+v0[3] + v1[0]+v1[1]+v1[2]+v1[3];
            float sq = v0[0]*v0[0]+v0[1]*v0[1]+v0[2]*v0[2]+v0[3]*v0[3]
                     + v1[0]*v1[0]+v1[1]*v1[1]+v1[2]*v1[2]+v1[3]*v1[3];
            s = wred_add(s); sq = wred_add(sq);
            float mean = s * (1.0f / 512.0f);
            float rstd = rsqrtf(sq * (1.0f / 512.0f) - mean * mean + 1e-5f);
            half8 hv;
            #pragma unroll
            for (int c = 0; c < 4; ++c) {
                float xa = (v0[c] - mean) * rstd * g1a[c] + e1a[c];
                float xb = (v1[c] - mean) * rstd * g1b[c] + e1b[c];
                hv[c]     = (_Float16)gelu_f(xa);
                hv[c + 4] = (_Float16)gelu_f(xb);
            }
            *(half8*)(smem + e * 1024 + ((l * 16) ^ ((e & 7) << 4))) = hv;
        }
    }
    __syncthreads();

    // ---- Phase B: (64x512 f16) @ (256x512 f16)^T via MFMA, fp32 accum
    // wave tiling: mg = w>>1 (2 m-tiles), ng = w&1 (8 n-tiles)
    f32x4 acc[2][8] = {};
    const int lg = l >> 4, lr = l & 15;
    {
        const int mg = w >> 1, ng = w & 1;
        const _Float16* wbase = w2h + (size_t)(ng * 128 + lr) * 512 + lg * 8;
        for (int kk = 0; kk < 16; ++kk) {
            half8 af[2];
            #pragma unroll
            for (int mi = 0; mi < 2; ++mi) {
                int er = (mg * 2 + mi) * 16 + lr;
                af[mi] = *(const half8*)(smem + er * 1024 + ((kk * 64 + lg * 16) ^ ((er & 7) << 4)));
            }
            half8 bf[8];
            #pragma unroll
            for (int n = 0; n < 8; ++n)
                bf[n] = *(const half8*)(wbase + (size_t)n * 16 * 512 + kk * 32);
            #pragma unroll
            for (int mi = 0; mi < 2; ++mi)
                #pragma unroll
                for (int n = 0; n < 8; ++n)
                    acc[mi][n] = __builtin_amdgcn_mfma_f32_16x16x32_f16(af[mi], bf[n], acc[mi][n], 0, 0, 0);
        }
    }
    __syncthreads();

    // ---- write h2 (+b2) into LDS (reuse), swizzled
    {
        const int mg = w >> 1, ng = w & 1;
        #pragma unroll
        for (int n = 0; n < 8; ++n) {
            int o = (ng * 8 + n) * 16 + lr;
            float bb = b2[o];
            #pragma unroll
            for (int mi = 0; mi < 2; ++mi)
                #pragma unroll
                for (int r = 0; r < 4; ++r) {
                    int er = (mg * 2 + mi) * 16 + lg * 4 + r;
                    *(float*)(smem + er * 1024 + ((o * 4) ^ ((er & 7) << 4))) = acc[mi][n][r] + bb;
                }
        }
    }
    __syncthreads();

    // ---- Phase C: LN2 + gelu + dot(w3) + sigmoid
    {
        const int o0 = l * 4;
        f32x4 g2v = *(const f32x4*)(g2 + o0);
        f32x4 e2v = *(const f32x4*)(be2 + o0);
        f32x4 w3v = *(const f32x4*)(w3 + o0);
        float b3s = b3[0];
        for (int el = 0; el < 16; ++el) {
            const int e = w * 16 + el;
            f32x4 h = *(const f32x4*)(smem + e * 1024 + ((l * 16) ^ ((e & 7) << 4)));
            float s  = h[0] + h[1] + h[2] + h[3];
            float sq = h[0]*h[0] + h[1]*h[1] + h[2]*h[2] + h[3]*h[3];
            s = wred_add(s); sq = wred_add(sq);
            float mean = s * (1.0f / 256.0f);
            float rstd = rsqrtf(sq * (1.0f / 256.0f) - mean * mean + 1e-5f);
            float part = 0.0f;
            #pragma unroll
            for (int c = 0; c < 4; ++c) {
                float xx = (h[c] - mean) * rstd * g2v[c] + e2v[c];
                part += gelu_f(xx) * w3v[c];
            }
            part = wred_add(part);
            if (l == 0)
                out[(size_t)b * E_ + eb * 64 + e] = 1.0f / (1.0f + __expf(-(part + b3s)));
        }
    }
}

// ---------------------------------------------------------------- launch
extern "C" void kernel_launch(void* const* d_in, const int* in_sizes, int n_in,
                              void* d_out, int out_size, void* d_ws, size_t ws_size,
                              hipStream_t stream) {
    const float* verts = (const float*)d_in[0];
    const float* wp    = (const float*)d_in[1];
    const float* bp    = (const float*)d_in[2];
    const float* in_w  = (const float*)d_in[3];
    const float* in_b  = (const float*)d_in[4];
    const float* out_w = (const float*)d_in[5];
    const float* out_b = (const float*)d_in[6];
    const float* w1    = (const float*)d_in[7];
    const float* b1    = (const float*)d_in[8];
    const float* g1    = (const float*)d_in[9];
    const float* be1   = (const float*)d_in[10];
    const float* w2    = (const float*)d_in[11];
    const float* b2    = (const float*)d_in[12];
    const float* g2    = (const float*)d_in[13];
    const float* be2   = (const float*)d_in[14];
    const float* w3    = (const float*)d_in[15];
    const float* b3    = (const float*)d_in[16];
    float* out = (float*)d_out;

    float* ws = (float*)d_ws;
    float* x    = ws;                    // 1024*512
    float* qkv  = ws + 524288;           // 1024*1536
    float* ctx  = ws + 2097152;          // 1024*512
    float* Amat = ws + 2621440;          // 1024*512
    float* Bmat = ws + 3145728;          // 1024*512
    _Float16* w2h = (_Float16*)((char*)d_ws + 14680064);   // 256*512 f16
    int2* etab    = (int2*)((char*)d_ws + 14942208);       // E_ int2

    k_vproj<<<dim3(2048), dim3(256), 0, stream>>>(verts, wp, bp, x);
    k_etab <<<dim3(128),  dim3(256), 0, stream>>>(etab);
    k_w2h  <<<dim3(512),  dim3(256), 0, stream>>>(w2, w2h);
    // qkv = x @ in_w^T + in_b
    k_gemm<<<dim3(24, 16), dim3(256), 0, stream>>>(x, in_w, in_b, nullptr, qkv,
                                                   1024, 1536, 512, 512, 0);
    k_attn<<<dim3(256), dim3(256), 0, stream>>>(qkv, ctx);
    // x = x + ctx @ out_w^T + out_b   (in place)
    k_gemm<<<dim3(8, 16), dim3(256), 0, stream>>>(ctx, out_w, out_b, x, x,
                                                  1024, 512, 512, 512, 0);
    // Amat = x @ w1[:, :512]^T + b1 ; Bmat = x @ w1[:, 512:]^T
    k_gemm<<<dim3(8, 16), dim3(256), 0, stream>>>(x, w1, b1, nullptr, Amat,
                                                  1024, 512, 512, 1024, 0);
    k_gemm<<<dim3(8, 16), dim3(256), 0, stream>>>(x, w1, nullptr, nullptr, Bmat,
                                                  1024, 512, 512, 1024, 512);
    k_edge<<<dim3(B_ * 510), dim3(256), 65536, stream>>>(Amat, Bmat, w2h,
                                                         g1, be1, b2, g2, be2, w3, b3,
                                                         etab, out);
}

// Round 2
// 503.451 us; speedup vs baseline: 1.0784x; 1.0784x over previous
//
#include <hip/hip_runtime.h>
#include <hip/hip_bf16.h>
#include <hip/hip_fp16.h>

#define B_  4
#define V_  256
#define H_  512
#define E_  32640   // V*(V-1)/2

typedef _Float16 half8 __attribute__((ext_vector_type(8)));
typedef float    f32x4 __attribute__((ext_vector_type(4)));

// Fast erf (Abramowitz-Stegun 7.1.26, |err| <= 1.5e-7), branchless.
__device__ __forceinline__ float gelu_f(float x) {
    float u = x * 0.70710678118654752f;
    float a = fabsf(u);
    float t = __builtin_amdgcn_rcpf(fmaf(0.3275911f, a, 1.0f));
    float poly = t * fmaf(t, fmaf(t, fmaf(t, fmaf(t, 1.061405429f, -1.453152027f),
                                          1.421413741f), -0.284496736f), 0.254829592f);
    float ex = __expf(-u * u);
    float erfa = fmaf(-poly, ex, 1.0f);           // erf(|u|)
    float erfu = copysignf(erfa, u);
    return 0.5f * x * (1.0f + erfu);
}

__device__ __forceinline__ float wred_add(float v) {
    #pragma unroll
    for (int off = 32; off > 0; off >>= 1) v += __shfl_xor(v, off, 64);
    return v;
}

__device__ __forceinline__ void split16(float v, _Float16* hi, _Float16* lo) {
    _Float16 h = (_Float16)v;
    *hi = h; *lo = (_Float16)(v - (float)h);
}

// ---------------------------------------------------------------- vproj (+ fp16 split of x)
__global__ void k_vproj(const float* __restrict__ verts, const float* __restrict__ wp,
                        const float* __restrict__ bp, float* __restrict__ x,
                        _Float16* __restrict__ xhi, _Float16* __restrict__ xlo) {
    int t = blockIdx.x * 256 + threadIdx.x;          // < 1024*512
    int bv = t >> 9, hh = t & 511;
    const float* vr = verts + bv * 3;
    const float* wr = wp + hh * 3;
    float val = vr[0] * wr[0] + vr[1] * wr[1] + vr[2] * wr[2] + bp[hh];
    x[t] = val;
    split16(val, xhi + t, xlo + t);
}

// ---------------------------------------------------------------- one-shot prep
// seg0: w2->f16 (131072) | seg1: etab (32640) | seg2: in_w split (786432)
// seg3: out_w split (262144) | seg4: w1 rearrange+split (524288)
__global__ void k_prep(const float* __restrict__ w2, _Float16* __restrict__ w2h,
                       int2* __restrict__ etab,
                       const float* __restrict__ in_w, _Float16* __restrict__ iwhi, _Float16* __restrict__ iwlo,
                       const float* __restrict__ out_w, _Float16* __restrict__ owhi, _Float16* __restrict__ owlo,
                       const float* __restrict__ w1, _Float16* __restrict__ w1hi, _Float16* __restrict__ w1lo) {
    int t = blockIdx.x * 256 + threadIdx.x;
    if (t < 131072) { w2h[t] = (_Float16)w2[t]; return; }
    t -= 131072;
    if (t < 32640) {
        double disc = (double)(2 * V_ - 1) * (2 * V_ - 1) - 8.0 * (double)t;
        int i = (int)((2 * V_ - 1 - sqrt(disc)) * 0.5);
        if (i < 0) i = 0;
        if (i > V_ - 2) i = V_ - 2;
        while (i < V_ - 2 && (i + 1) * (2 * V_ - 1 - (i + 1)) / 2 <= t) ++i;
        while (i > 0 && i * (2 * V_ - 1 - i) / 2 > t) --i;
        int j = t - i * (2 * V_ - 1 - i) / 2 + i + 1;
        etab[t] = make_int2(i, j);
        return;
    }
    t -= 32640;
    if (t < 786432) { split16(in_w[t], iwhi + t, iwlo + t); return; }
    t -= 786432;
    if (t < 262144) { split16(out_w[t], owhi + t, owlo + t); return; }
    t -= 262144;
    if (t < 524288) {
        int r = t >> 9, k = t & 511;
        float v = (r < 512) ? w1[r * 1024 + k] : w1[(r - 512) * 1024 + 512 + k];
        split16(v, w1hi + t, w1lo + t);
    }
}

// ---------------------------------------------------------------- split-fp16 MFMA GEMM
// C[M,*] = A[M,512] @ W[*,512]^T via (hi+lo) x (hi+lo), 3 MFMA products (~fp32 acc).
// MODE 0: C fp32 = .. + bias                          (qkv)
// MODE 1: C fp32 = .. + bias + res; also Chi/Clo      (out-proj, in-place x)
// MODE 2: cols<512 -> C(+bias)/Chi ; cols>=512 -> C2/C2h   (Amat/Ah, Bmat/Bh)
template<int MODE>
__global__ __launch_bounds__(256) void k_gemm_sp(
        const _Float16* __restrict__ Ahi, const _Float16* __restrict__ Alo,
        const _Float16* __restrict__ Whi, const _Float16* __restrict__ Wlo,
        const float* __restrict__ bias, const float* __restrict__ res,
        float* __restrict__ C, _Float16* __restrict__ Chi, _Float16* __restrict__ Clo,
        float* __restrict__ C2, _Float16* __restrict__ C2h, int N)
{
    const int tid = threadIdx.x;
    const int w = tid >> 6, l = tid & 63;
    const int lr = l & 15, lg = l >> 4;
    const int mg = w >> 1, ng = w & 1;
    const int row0 = blockIdx.y * 64 + mg * 32;
    const int col0 = blockIdx.x * 64 + ng * 32;

    f32x4 acc[2][2] = {};
    for (int kk = 0; kk < 16; ++kk) {
        const int ko = kk * 32 + lg * 8;
        half8 ah[2], al[2], bh[2], bl[2];
        #pragma unroll
        for (int mi = 0; mi < 2; ++mi) {
            size_t off = (size_t)(row0 + mi * 16 + lr) * 512 + ko;
            ah[mi] = *(const half8*)(Ahi + off);
            al[mi] = *(const half8*)(Alo + off);
        }
        #pragma unroll
        for (int ni = 0; ni < 2; ++ni) {
            size_t off = (size_t)(col0 + ni * 16 + lr) * 512 + ko;
            bh[ni] = *(const half8*)(Whi + off);
            bl[ni] = *(const half8*)(Wlo + off);
        }
        #pragma unroll
        for (int mi = 0; mi < 2; ++mi)
            #pragma unroll
            for (int ni = 0; ni < 2; ++ni) {
                acc[mi][ni] = __builtin_amdgcn_mfma_f32_16x16x32_f16(ah[mi], bh[ni], acc[mi][ni], 0, 0, 0);
                acc[mi][ni] = __builtin_amdgcn_mfma_f32_16x16x32_f16(ah[mi], bl[ni], acc[mi][ni], 0, 0, 0);
                acc[mi][ni] = __builtin_amdgcn_mfma_f32_16x16x32_f16(al[mi], bh[ni], acc[mi][ni], 0, 0, 0);
            }
    }
    #pragma unroll
    for (int mi = 0; mi < 2; ++mi)
        #pragma unroll
        for (int ni = 0; ni < 2; ++ni)
            #pragma unroll
            for (int r = 0; r < 4; ++r) {
                int row = row0 + mi * 16 + lg * 4 + r;
                int col = col0 + ni * 16 + lr;
                float v = acc[mi][ni][r];
                if (MODE == 0) {
                    v += bias[col];
                    C[(size_t)row * N + col] = v;
                } else if (MODE == 1) {
                    size_t idx = (size_t)row * 512 + col;
                    v += bias[col] + res[idx];
                    C[idx] = v;
                    split16(v, Chi + idx, Clo + idx);
                } else {
                    if (col < 512) {
                        size_t idx = (size_t)row * 512 + col;
                        v += bias[col];
                        C[idx] = v;
                        Chi[idx] = (_Float16)v;
                    } else {
                        size_t idx = (size_t)row * 512 + (col - 512);
                        C2[idx] = v;
                        C2h[idx] = (_Float16)v;
                    }
                }
            }
}

// ---------------------------------------------------------------- attention (fp32, split outputs)
__global__ __launch_bounds__(256) void k_attn(const float* __restrict__ qkv,
                                              _Float16* __restrict__ ctxhi,
                                              _Float16* __restrict__ ctxlo) {
    const int bid = blockIdx.x;
    const int qg = bid & 7, h = (bid >> 3) & 7, b = bid >> 6;
    const int tid = threadIdx.x;
    const int q = tid & 31, g = tid >> 5;
    const int qi = qg * 32 + q;
    const float* qrow = qkv + ((size_t)(b * V_ + qi)) * 1536 + h * 64;
    float qreg[64];
    #pragma unroll
    for (int dd = 0; dd < 16; ++dd) {
        f32x4 t4 = *(const f32x4*)(qrow + dd * 4);
        qreg[dd*4+0]=t4[0]; qreg[dd*4+1]=t4[1]; qreg[dd*4+2]=t4[2]; qreg[dd*4+3]=t4[3];
    }
    float m = -1e30f, lsum = 0.0f;
    float cacc[64];
    #pragma unroll
    for (int d = 0; d < 64; ++d) cacc[d] = 0.0f;
    for (int kk = 0; kk < 32; ++kk) {
        const int kr = g * 32 + kk;
        const float* krow = qkv + ((size_t)(b * V_ + kr)) * 1536 + 512 + h * 64;
        float s = 0.0f;
        #pragma unroll
        for (int dd = 0; dd < 16; ++dd) {
            f32x4 kv = *(const f32x4*)(krow + dd * 4);
            s += qreg[dd*4+0]*kv[0] + qreg[dd*4+1]*kv[1] + qreg[dd*4+2]*kv[2] + qreg[dd*4+3]*kv[3];
        }
        s *= 0.125f;
        float mn = fmaxf(m, s);
        float scale = __expf(m - mn);
        float p = __expf(s - mn);
        lsum = lsum * scale + p;
        const float* vrow = qkv + ((size_t)(b * V_ + kr)) * 1536 + 1024 + h * 64;
        #pragma unroll
        for (int dd = 0; dd < 16; ++dd) {
            f32x4 vv = *(const f32x4*)(vrow + dd * 4);
            #pragma unroll
            for (int c = 0; c < 4; ++c)
                cacc[dd*4+c] = cacc[dd*4+c] * scale + p * vv[c];
        }
        m = mn;
    }
    __shared__ float mls[8][32][2];
    __shared__ float cbuf[8][32][16];
    mls[g][q][0] = m; mls[g][q][1] = lsum;
    __syncthreads();
    float M = -1e30f;
    #pragma unroll
    for (int gg = 0; gg < 8; ++gg) M = fmaxf(M, mls[gg][q][0]);
    float L = 0.0f;
    #pragma unroll
    for (int gg = 0; gg < 8; ++gg) L += mls[gg][q][1] * __expf(mls[gg][q][0] - M);
    const float myscale = __expf(m - M) / L;
    for (int c = 0; c < 4; ++c) {
        #pragma unroll
        for (int d = 0; d < 16; ++d) cbuf[g][q][d] = cacc[c * 16 + d] * myscale;
        __syncthreads();
        for (int idx = tid; idx < 512; idx += 256) {
            int qq = idx >> 4, d = idx & 15;
            float sum = 0.0f;
            #pragma unroll
            for (int gg = 0; gg < 8; ++gg) sum += cbuf[gg][qq][d];
            size_t oidx = ((size_t)(b * V_ + qg * 32 + qq)) * 512 + h * 64 + c * 16 + d;
            split16(sum, ctxhi + oidx, ctxlo + oidx);
        }
        __syncthreads();
    }
}

// ---------------------------------------------------------------- per-row stats of Amat/Bmat
__global__ __launch_bounds__(256) void k_rowstats(const float* __restrict__ Amat,
                                                  const float* __restrict__ Bmat,
                                                  float2* __restrict__ statsA,
                                                  float2* __restrict__ statsB) {
    const int g = threadIdx.x >> 6, l = threadIdx.x & 63;
    const int m = blockIdx.x * 4 + g;                 // 0..2047
    const float* src = (m < 1024 ? Amat + (size_t)m * 512 : Bmat + (size_t)(m - 1024) * 512);
    f32x4 v0 = *(const f32x4*)(src + l * 8);
    f32x4 v1 = *(const f32x4*)(src + l * 8 + 4);
    float s  = v0[0]+v0[1]+v0[2]+v0[3] + v1[0]+v1[1]+v1[2]+v1[3];
    float sq = v0[0]*v0[0]+v0[1]*v0[1]+v0[2]*v0[2]+v0[3]*v0[3]
             + v1[0]*v1[0]+v1[1]*v1[1]+v1[2]*v1[2]+v1[3]*v1[3];
    s = wred_add(s); sq = wred_add(sq);
    if (l == 0) {
        if (m < 1024) statsA[m] = make_float2(s, sq);
        else          statsB[m - 1024] = make_float2(s, sq);
    }
}

// ---------------------------------------------------------------- pair dots P[b][i][j] = Ah_i . Bh_j
__global__ __launch_bounds__(256) void k_pair(const _Float16* __restrict__ Ah,
                                              const _Float16* __restrict__ Bh,
                                              float* __restrict__ P) {
    const int t = blockIdx.x * 4 + (threadIdx.x >> 6);   // 1024 tiles
    const int b = t >> 8, tt = t & 255;
    const int i0 = (tt >> 4) * 16, j0 = (tt & 15) * 16;
    const int l = threadIdx.x & 63, lr = l & 15, lg = l >> 4;
    f32x4 acc = {};
    for (int kk = 0; kk < 16; ++kk) {
        const int ko = kk * 32 + lg * 8;
        half8 af = *(const half8*)(Ah + (size_t)(b * 256 + i0 + lr) * 512 + ko);
        half8 bf = *(const half8*)(Bh + (size_t)(b * 256 + j0 + lr) * 512 + ko);
        acc = __builtin_amdgcn_mfma_f32_16x16x32_f16(af, bf, acc, 0, 0, 0);
    }
    #pragma unroll
    for (int r = 0; r < 4; ++r)
        P[(size_t)b * 65536 + (size_t)(i0 + lg * 4 + r) * 256 + j0 + lr] = acc[r];
}

// ---------------------------------------------------------------- fused edge MLP
// grid = B*510 (64 edges/block), 256 thr = 4 waves, 64KB dynamic LDS (g -> h2 reuse)
__global__ __launch_bounds__(256) void k_edge(
        const float* __restrict__ Am, const float* __restrict__ Bm,
        const _Float16* __restrict__ w2h,
        const float* __restrict__ g1, const float* __restrict__ be1,
        const float* __restrict__ b2, const float* __restrict__ g2,
        const float* __restrict__ be2, const float* __restrict__ w3,
        const float* __restrict__ b3, const int2* __restrict__ etab,
        const float2* __restrict__ statsA, const float2* __restrict__ statsB,
        const float* __restrict__ P, float* __restrict__ out)
{
    extern __shared__ unsigned char smem[];   // 64KB: [64][512] f16 g  ->  [64][256] f32 h2
    const int tid = threadIdx.x;
    const int w = tid >> 6;
    const int l = tid & 63;
    const int b  = blockIdx.x / 510;
    const int eb = blockIdx.x % 510;

    // ---- per-edge LN1 stats from precomputed row sums + pair dot (no reductions)
    int   roffA[16], roffB[16];
    float emean[16], erstd[16];
    #pragma unroll
    for (int el = 0; el < 16; ++el) {
        int2 ij = etab[eb * 64 + w * 16 + el];
        float2 sa = statsA[b * 256 + ij.x];
        float2 sb = statsB[b * 256 + ij.y];
        float pij = P[(size_t)b * 65536 + (size_t)ij.x * 256 + ij.y];
        float mean = (sa.x + sb.x) * (1.0f / 512.0f);
        float ex2  = (sa.y + sb.y + 2.0f * pij) * (1.0f / 512.0f);
        emean[el] = mean;
        erstd[el] = rsqrtf(ex2 - mean * mean + 1e-5f);
        roffA[el] = (b * 256 + ij.x) << 9;
        roffB[el] = (b * 256 + ij.y) << 9;
    }

    // ---- Phase A: g = gelu(LN1(A_i + B_j)) -> fp16 LDS (XOR-swizzled), pure elementwise
    {
        const int d0 = l * 8;
        f32x4 g1a = *(const f32x4*)(g1 + d0);
        f32x4 g1b = *(const f32x4*)(g1 + d0 + 4);
        f32x4 e1a = *(const f32x4*)(be1 + d0);
        f32x4 e1b = *(const f32x4*)(be1 + d0 + 4);
        #pragma unroll
        for (int el = 0; el < 16; ++el) {
            const int e = w * 16 + el;
            const float* ar = Am + roffA[el] + d0;
            const float* br = Bm + roffB[el] + d0;
            f32x4 a0 = *(const f32x4*)ar, a1 = *(const f32x4*)(ar + 4);
            f32x4 c0 = *(const f32x4*)br, c1 = *(const f32x4*)(br + 4);
            f32x4 v0 = a0 + c0, v1 = a1 + c1;
            const float mean = emean[el], rstd = erstd[el];
            half8 hv;
            #pragma unroll
            for (int c = 0; c < 4; ++c) {
                float xa = (v0[c] - mean) * rstd * g1a[c] + e1a[c];
                float xb = (v1[c] - mean) * rstd * g1b[c] + e1b[c];
                hv[c]     = (_Float16)gelu_f(xa);
                hv[c + 4] = (_Float16)gelu_f(xb);
            }
            *(half8*)(smem + e * 1024 + ((l * 16) ^ ((e & 7) << 4))) = hv;
        }
    }
    __syncthreads();

    // ---- Phase B: (64x512 f16) @ (256x512 f16)^T via MFMA, fp32 accum
    f32x4 acc[2][8] = {};
    const int lg = l >> 4, lr = l & 15;
    {
        const int mg = w >> 1, ng = w & 1;
        const _Float16* wbase = w2h + (size_t)(ng * 128 + lr) * 512 + lg * 8;
        for (int kk = 0; kk < 16; ++kk) {
            half8 af[2];
            #pragma unroll
            for (int mi = 0; mi < 2; ++mi) {
                int er = (mg * 2 + mi) * 16 + lr;
                af[mi] = *(const half8*)(smem + er * 1024 + ((kk * 64 + lg * 16) ^ ((er & 7) << 4)));
            }
            half8 bf[8];
            #pragma unroll
            for (int n = 0; n < 8; ++n)
                bf[n] = *(const half8*)(wbase + (size_t)n * 16 * 512 + kk * 32);
            #pragma unroll
            for (int mi = 0; mi < 2; ++mi)
                #pragma unroll
                for (int n = 0; n < 8; ++n)
                    acc[mi][n] = __builtin_amdgcn_mfma_f32_16x16x32_f16(af[mi], bf[n], acc[mi][n], 0, 0, 0);
        }
    }
    __syncthreads();

    // ---- write h2 (+b2) into LDS (reuse), swizzled
    {
        const int mg = w >> 1, ng = w & 1;
        #pragma unroll
        for (int n = 0; n < 8; ++n) {
            int o = (ng * 8 + n) * 16 + lr;
            float bb = b2[o];
            #pragma unroll
            for (int mi = 0; mi < 2; ++mi)
                #pragma unroll
                for (int r = 0; r < 4; ++r) {
                    int er = (mg * 2 + mi) * 16 + lg * 4 + r;
                    *(float*)(smem + er * 1024 + ((o * 4) ^ ((er & 7) << 4))) = acc[mi][n][r] + bb;
                }
        }
    }
    __syncthreads();

    // ---- Phase C: LN2 + gelu + dot(w3) + sigmoid
    {
        const int o0 = l * 4;
        f32x4 g2v = *(const f32x4*)(g2 + o0);
        f32x4 e2v = *(const f32x4*)(be2 + o0);
        f32x4 w3v = *(const f32x4*)(w3 + o0);
        float b3s = b3[0];
        for (int el = 0; el < 16; ++el) {
            const int e = w * 16 + el;
            f32x4 h = *(const f32x4*)(smem + e * 1024 + ((l * 16) ^ ((e & 7) << 4)));
            float s  = h[0] + h[1] + h[2] + h[3];
            float sq = h[0]*h[0] + h[1]*h[1] + h[2]*h[2] + h[3]*h[3];
            s = wred_add(s); sq = wred_add(sq);
            float mean = s * (1.0f / 256.0f);
            float rstd = rsqrtf(sq * (1.0f / 256.0f) - mean * mean + 1e-5f);
            float part = 0.0f;
            #pragma unroll
            for (int c = 0; c < 4; ++c) {
                float xx = (h[c] - mean) * rstd * g2v[c] + e2v[c];
                part += gelu_f(xx) * w3v[c];
            }
            part = wred_add(part);
            if (l == 0)
                out[(size_t)b * E_ + eb * 64 + e] = 1.0f / (1.0f + __expf(-(part + b3s)));
        }
    }
}

// ---------------------------------------------------------------- launch
extern "C" void kernel_launch(void* const* d_in, const int* in_sizes, int n_in,
                              void* d_out, int out_size, void* d_ws, size_t ws_size,
                              hipStream_t stream) {
    const float* verts = (const float*)d_in[0];
    const float* wp    = (const float*)d_in[1];
    const float* bp    = (const float*)d_in[2];
    const float* in_w  = (const float*)d_in[3];
    const float* in_b  = (const float*)d_in[4];
    const float* out_w = (const float*)d_in[5];
    const float* out_b = (const float*)d_in[6];
    const float* w1    = (const float*)d_in[7];
    const float* b1    = (const float*)d_in[8];
    const float* g1    = (const float*)d_in[9];
    const float* be1   = (const float*)d_in[10];
    const float* w2    = (const float*)d_in[11];
    const float* b2    = (const float*)d_in[12];
    const float* g2    = (const float*)d_in[13];
    const float* be2   = (const float*)d_in[14];
    const float* w3    = (const float*)d_in[15];
    const float* b3    = (const float*)d_in[16];
    float* out = (float*)d_out;

    const size_t MB = 1 << 20;
    char* W = (char*)d_ws;
    float*    x     = (float*)(W + 0);                 // 2MB
    _Float16* xhi   = (_Float16*)(W + 2*MB);           // 1MB
    _Float16* xlo   = (_Float16*)(W + 3*MB);           // 1MB
    float*    qkv   = (float*)(W + 4*MB);              // 6MB (dead after attn)
    float*    Amat  = (float*)(W + 4*MB);              // 2MB  (reuse qkv)
    float*    Bmat  = (float*)(W + 6*MB);              // 2MB
    _Float16* Ah    = (_Float16*)(W + 8*MB);           // 1MB
    _Float16* Bh    = (_Float16*)(W + 9*MB);           // 1MB
    _Float16* ctxhi = (_Float16*)(W + 10*MB);          // 1MB
    _Float16* ctxlo = (_Float16*)(W + 11*MB);          // 1MB
    _Float16* w2h   = (_Float16*)(W + 12*MB);          // 256KB
    int2*     etab  = (int2*)(W + 12*MB + 256*1024);   // 256KB
    float2*   statsA= (float2*)(W + 12*MB + 512*1024); // 8KB
    float2*   statsB= (float2*)(W + 12*MB + 520*1024); // 8KB
    _Float16* iwhi  = (_Float16*)(W + 13*MB);          // 1.5MB
    _Float16* iwlo  = (_Float16*)(W + 13*MB + 1536*1024);
    _Float16* owhi  = (_Float16*)(W + 16*MB);          // 0.5MB
    _Float16* owlo  = (_Float16*)(W + 16*MB + 512*1024);
    _Float16* w1hi  = (_Float16*)(W + 17*MB);          // 1MB
    _Float16* w1lo  = (_Float16*)(W + 18*MB);          // 1MB
    float*    P     = (float*)(W + 19*MB);             // 1MB

    k_vproj<<<dim3(2048), dim3(256), 0, stream>>>(verts, wp, bp, x, xhi, xlo);
    k_prep <<<dim3(6784), dim3(256), 0, stream>>>(w2, w2h, etab, in_w, iwhi, iwlo,
                                                  out_w, owhi, owlo, w1, w1hi, w1lo);
    // qkv = x @ in_w^T + in_b
    k_gemm_sp<0><<<dim3(24, 16), dim3(256), 0, stream>>>(xhi, xlo, iwhi, iwlo, in_b, nullptr,
                                                         qkv, nullptr, nullptr, nullptr, nullptr, 1536);
    k_attn<<<dim3(256), dim3(256), 0, stream>>>(qkv, ctxhi, ctxlo);
    // x = x + ctx @ out_w^T + out_b (in place) ; also refresh xhi/xlo
    k_gemm_sp<1><<<dim3(8, 16), dim3(256), 0, stream>>>(ctxhi, ctxlo, owhi, owlo, out_b, x,
                                                        x, xhi, xlo, nullptr, nullptr, 512);
    // Amat = x @ w1[:, :512]^T + b1 ; Bmat = x @ w1[:, 512:]^T  (+ fp16 copies)
    k_gemm_sp<2><<<dim3(16, 16), dim3(256), 0, stream>>>(xhi, xlo, w1hi, w1lo, b1, nullptr,
                                                         Amat, Ah, nullptr, Bmat, Bh, 512);
    k_rowstats<<<dim3(512), dim3(256), 0, stream>>>(Amat, Bmat, statsA, statsB);
    k_pair<<<dim3(256), dim3(256), 0, stream>>>(Ah, Bh, P);
    k_edge<<<dim3(B_ * 510), dim3(256), 65536, stream>>>(Amat, Bmat, w2h,
                                                         g1, be1, b2, g2, be2, w3, b3,
                                                         etab, statsA, statsB, P, out);
}

// Round 3
// 333.410 us; speedup vs baseline: 1.6284x; 1.5100x over previous
//
#include <hip/hip_runtime.h>
#include <hip/hip_bf16.h>
#include <hip/hip_fp16.h>

#define B_  4
#define V_  256
#define H_  512
#define E_  32640   // V*(V-1)/2

typedef _Float16 half8 __attribute__((ext_vector_type(8)));
typedef float    f32x4 __attribute__((ext_vector_type(4)));

// Fast erf (Abramowitz-Stegun 7.1.26, |err| <= 1.5e-7), branchless.
__device__ __forceinline__ float gelu_f(float x) {
    float u = x * 0.70710678118654752f;
    float a = fabsf(u);
    float t = __builtin_amdgcn_rcpf(fmaf(0.3275911f, a, 1.0f));
    float poly = t * fmaf(t, fmaf(t, fmaf(t, fmaf(t, 1.061405429f, -1.453152027f),
                                          1.421413741f), -0.284496736f), 0.254829592f);
    float ex = __expf(-u * u);
    float erfa = fmaf(-poly, ex, 1.0f);           // erf(|u|)
    float erfu = copysignf(erfa, u);
    return 0.5f * x * (1.0f + erfu);
}

__device__ __forceinline__ float wred_add(float v) {
    #pragma unroll
    for (int off = 32; off > 0; off >>= 1) v += __shfl_xor(v, off, 64);
    return v;
}

__device__ __forceinline__ void split16(float v, _Float16* hi, _Float16* lo) {
    _Float16 h = (_Float16)v;
    *hi = h; *lo = (_Float16)(v - (float)h);
}

// ---------------------------------------------------------------- vproj (+ fp16 split of x)
__global__ void k_vproj(const float* __restrict__ verts, const float* __restrict__ wp,
                        const float* __restrict__ bp, float* __restrict__ x,
                        _Float16* __restrict__ xhi, _Float16* __restrict__ xlo) {
    int t = blockIdx.x * 256 + threadIdx.x;          // < 1024*512
    int bv = t >> 9, hh = t & 511;
    const float* vr = verts + bv * 3;
    const float* wr = wp + hh * 3;
    float val = vr[0] * wr[0] + vr[1] * wr[1] + vr[2] * wr[2] + bp[hh];
    x[t] = val;
    split16(val, xhi + t, xlo + t);
}

// ---------------------------------------------------------------- one-shot prep
// seg0: w2 -> w2f fragment-major fp16 (131072) | seg1: etab (32640)
// seg2: in_w split (786432) | seg3: out_w split (262144) | seg4: w1 rearrange+split (524288)
__global__ void k_prep(const float* __restrict__ w2, _Float16* __restrict__ w2f,
                       int2* __restrict__ etab,
                       const float* __restrict__ in_w, _Float16* __restrict__ iwhi, _Float16* __restrict__ iwlo,
                       const float* __restrict__ out_w, _Float16* __restrict__ owhi, _Float16* __restrict__ owlo,
                       const float* __restrict__ w1, _Float16* __restrict__ w1hi, _Float16* __restrict__ w1lo) {
    int t = blockIdx.x * 256 + threadIdx.x;
    if (t < 131072) {
        // w2f[kgroup=k/8][col][k%8] = w2[col][k]   (MFMA B-fragment order)
        int col = t >> 9, k = t & 511;
        w2f[(size_t)(k >> 3) * 2048 + col * 8 + (k & 7)] = (_Float16)w2[t];
        return;
    }
    t -= 131072;
    if (t < 32640) {
        double disc = (double)(2 * V_ - 1) * (2 * V_ - 1) - 8.0 * (double)t;
        int i = (int)((2 * V_ - 1 - sqrt(disc)) * 0.5);
        if (i < 0) i = 0;
        if (i > V_ - 2) i = V_ - 2;
        while (i < V_ - 2 && (i + 1) * (2 * V_ - 1 - (i + 1)) / 2 <= t) ++i;
        while (i > 0 && i * (2 * V_ - 1 - i) / 2 > t) --i;
        int j = t - i * (2 * V_ - 1 - i) / 2 + i + 1;
        etab[t] = make_int2(i, j);
        return;
    }
    t -= 32640;
    if (t < 786432) { split16(in_w[t], iwhi + t, iwlo + t); return; }
    t -= 786432;
    if (t < 262144) { split16(out_w[t], owhi + t, owlo + t); return; }
    t -= 262144;
    if (t < 524288) {
        int r = t >> 9, k = t & 511;
        float v = (r < 512) ? w1[r * 1024 + k] : w1[(r - 512) * 1024 + 512 + k];
        split16(v, w1hi + t, w1lo + t);
    }
}

// ---------------------------------------------------------------- split-fp16 MFMA GEMM
template<int MODE>
__global__ __launch_bounds__(256) void k_gemm_sp(
        const _Float16* __restrict__ Ahi, const _Float16* __restrict__ Alo,
        const _Float16* __restrict__ Whi, const _Float16* __restrict__ Wlo,
        const float* __restrict__ bias, const float* __restrict__ res,
        float* __restrict__ C, _Float16* __restrict__ Chi, _Float16* __restrict__ Clo,
        float* __restrict__ C2, _Float16* __restrict__ C2h, int N)
{
    const int tid = threadIdx.x;
    const int w = tid >> 6, l = tid & 63;
    const int lr = l & 15, lg = l >> 4;
    const int mg = w >> 1, ng = w & 1;
    const int row0 = blockIdx.y * 64 + mg * 32;
    const int col0 = blockIdx.x * 64 + ng * 32;

    f32x4 acc[2][2] = {};
    for (int kk = 0; kk < 16; ++kk) {
        const int ko = kk * 32 + lg * 8;
        half8 ah[2], al[2], bh[2], bl[2];
        #pragma unroll
        for (int mi = 0; mi < 2; ++mi) {
            size_t off = (size_t)(row0 + mi * 16 + lr) * 512 + ko;
            ah[mi] = *(const half8*)(Ahi + off);
            al[mi] = *(const half8*)(Alo + off);
        }
        #pragma unroll
        for (int ni = 0; ni < 2; ++ni) {
            size_t off = (size_t)(col0 + ni * 16 + lr) * 512 + ko;
            bh[ni] = *(const half8*)(Whi + off);
            bl[ni] = *(const half8*)(Wlo + off);
        }
        #pragma unroll
        for (int mi = 0; mi < 2; ++mi)
            #pragma unroll
            for (int ni = 0; ni < 2; ++ni) {
                acc[mi][ni] = __builtin_amdgcn_mfma_f32_16x16x32_f16(ah[mi], bh[ni], acc[mi][ni], 0, 0, 0);
                acc[mi][ni] = __builtin_amdgcn_mfma_f32_16x16x32_f16(ah[mi], bl[ni], acc[mi][ni], 0, 0, 0);
                acc[mi][ni] = __builtin_amdgcn_mfma_f32_16x16x32_f16(al[mi], bh[ni], acc[mi][ni], 0, 0, 0);
            }
    }
    #pragma unroll
    for (int mi = 0; mi < 2; ++mi)
        #pragma unroll
        for (int ni = 0; ni < 2; ++ni)
            #pragma unroll
            for (int r = 0; r < 4; ++r) {
                int row = row0 + mi * 16 + lg * 4 + r;
                int col = col0 + ni * 16 + lr;
                float v = acc[mi][ni][r];
                if (MODE == 0) {
                    v += bias[col];
                    C[(size_t)row * N + col] = v;
                } else if (MODE == 1) {
                    size_t idx = (size_t)row * 512 + col;
                    v += bias[col] + res[idx];
                    C[idx] = v;
                    split16(v, Chi + idx, Clo + idx);
                } else {
                    if (col < 512) {
                        size_t idx = (size_t)row * 512 + col;
                        v += bias[col];
                        C[idx] = v;
                        Chi[idx] = (_Float16)v;
                    } else {
                        size_t idx = (size_t)row * 512 + (col - 512);
                        C2[idx] = v;
                        C2h[idx] = (_Float16)v;
                    }
                }
            }
}

// ---------------------------------------------------------------- attention (fp32, split outputs)
__global__ __launch_bounds__(256) void k_attn(const float* __restrict__ qkv,
                                              _Float16* __restrict__ ctxhi,
                                              _Float16* __restrict__ ctxlo) {
    const int bid = blockIdx.x;
    const int qg = bid & 7, h = (bid >> 3) & 7, b = bid >> 6;
    const int tid = threadIdx.x;
    const int q = tid & 31, g = tid >> 5;
    const int qi = qg * 32 + q;
    const float* qrow = qkv + ((size_t)(b * V_ + qi)) * 1536 + h * 64;
    float qreg[64];
    #pragma unroll
    for (int dd = 0; dd < 16; ++dd) {
        f32x4 t4 = *(const f32x4*)(qrow + dd * 4);
        qreg[dd*4+0]=t4[0]; qreg[dd*4+1]=t4[1]; qreg[dd*4+2]=t4[2]; qreg[dd*4+3]=t4[3];
    }
    float m = -1e30f, lsum = 0.0f;
    float cacc[64];
    #pragma unroll
    for (int d = 0; d < 64; ++d) cacc[d] = 0.0f;
    for (int kk = 0; kk < 32; ++kk) {
        const int kr = g * 32 + kk;
        const float* krow = qkv + ((size_t)(b * V_ + kr)) * 1536 + 512 + h * 64;
        float s = 0.0f;
        #pragma unroll
        for (int dd = 0; dd < 16; ++dd) {
            f32x4 kv = *(const f32x4*)(krow + dd * 4);
            s += qreg[dd*4+0]*kv[0] + qreg[dd*4+1]*kv[1] + qreg[dd*4+2]*kv[2] + qreg[dd*4+3]*kv[3];
        }
        s *= 0.125f;
        float mn = fmaxf(m, s);
        float scale = __expf(m - mn);
        float p = __expf(s - mn);
        lsum = lsum * scale + p;
        const float* vrow = qkv + ((size_t)(b * V_ + kr)) * 1536 + 1024 + h * 64;
        #pragma unroll
        for (int dd = 0; dd < 16; ++dd) {
            f32x4 vv = *(const f32x4*)(vrow + dd * 4);
            #pragma unroll
            for (int c = 0; c < 4; ++c)
                cacc[dd*4+c] = cacc[dd*4+c] * scale + p * vv[c];
        }
        m = mn;
    }
    __shared__ float mls[8][32][2];
    __shared__ float cbuf[8][32][16];
    mls[g][q][0] = m; mls[g][q][1] = lsum;
    __syncthreads();
    float M = -1e30f;
    #pragma unroll
    for (int gg = 0; gg < 8; ++gg) M = fmaxf(M, mls[gg][q][0]);
    float L = 0.0f;
    #pragma unroll
    for (int gg = 0; gg < 8; ++gg) L += mls[gg][q][1] * __expf(mls[gg][q][0] - M);
    const float myscale = __expf(m - M) / L;
    for (int c = 0; c < 4; ++c) {
        #pragma unroll
        for (int d = 0; d < 16; ++d) cbuf[g][q][d] = cacc[c * 16 + d] * myscale;
        __syncthreads();
        for (int idx = tid; idx < 512; idx += 256) {
            int qq = idx >> 4, d = idx & 15;
            float sum = 0.0f;
            #pragma unroll
            for (int gg = 0; gg < 8; ++gg) sum += cbuf[gg][qq][d];
            size_t oidx = ((size_t)(b * V_ + qg * 32 + qq)) * 512 + h * 64 + c * 16 + d;
            split16(sum, ctxhi + oidx, ctxlo + oidx);
        }
        __syncthreads();
    }
}

// ---------------------------------------------------------------- per-row stats of Amat/Bmat
__global__ __launch_bounds__(256) void k_rowstats(const float* __restrict__ Amat,
                                                  const float* __restrict__ Bmat,
                                                  float2* __restrict__ statsA,
                                                  float2* __restrict__ statsB) {
    const int g = threadIdx.x >> 6, l = threadIdx.x & 63;
    const int m = blockIdx.x * 4 + g;                 // 0..2047
    const float* src = (m < 1024 ? Amat + (size_t)m * 512 : Bmat + (size_t)(m - 1024) * 512);
    f32x4 v0 = *(const f32x4*)(src + l * 8);
    f32x4 v1 = *(const f32x4*)(src + l * 8 + 4);
    float s  = v0[0]+v0[1]+v0[2]+v0[3] + v1[0]+v1[1]+v1[2]+v1[3];
    float sq = v0[0]*v0[0]+v0[1]*v0[1]+v0[2]*v0[2]+v0[3]*v0[3]
             + v1[0]*v1[0]+v1[1]*v1[1]+v1[2]*v1[2]+v1[3]*v1[3];
    s = wred_add(s); sq = wred_add(sq);
    if (l == 0) {
        if (m < 1024) statsA[m] = make_float2(s, sq);
        else          statsB[m - 1024] = make_float2(s, sq);
    }
}

// ---------------------------------------------------------------- pair dots P[b][i][j] = Ah_i . Bh_j
__global__ __launch_bounds__(256) void k_pair(const _Float16* __restrict__ Ah,
                                              const _Float16* __restrict__ Bh,
                                              float* __restrict__ P) {
    const int t = blockIdx.x * 4 + (threadIdx.x >> 6);   // 1024 tiles
    const int b = t >> 8, tt = t & 255;
    const int i0 = (tt >> 4) * 16, j0 = (tt & 15) * 16;
    const int l = threadIdx.x & 63, lr = l & 15, lg = l >> 4;
    f32x4 acc = {};
    for (int kk = 0; kk < 16; ++kk) {
        const int ko = kk * 32 + lg * 8;
        half8 af = *(const half8*)(Ah + (size_t)(b * 256 + i0 + lr) * 512 + ko);
        half8 bf = *(const half8*)(Bh + (size_t)(b * 256 + j0 + lr) * 512 + ko);
        acc = __builtin_amdgcn_mfma_f32_16x16x32_f16(af, bf, acc, 0, 0, 0);
    }
    #pragma unroll
    for (int r = 0; r < 4; ++r)
        P[(size_t)b * 65536 + (size_t)(i0 + lg * 4 + r) * 256 + j0 + lr] = acc[r];
}

// ---------------------------------------------------------------- fused edge MLP (v3)
// grid = B*510 (64 edges/block), 512 threads = 8 waves, 64KB dynamic LDS.
// Wave w owns output cols [32w, 32w+32) for ALL 64 edges -> w2 read once/block.
// LDS: g as [kgroup 0..63][edge 0..63] half8, edge XOR-swizzled by (kgroup&7).
//      After Phase B, buffer reused as h2 [64 edges][256 cols] f32.
__global__ __launch_bounds__(512, 4) void k_edge(
        const float* __restrict__ Am, const float* __restrict__ Bm,
        const _Float16* __restrict__ w2f,
        const float* __restrict__ g1, const float* __restrict__ be1,
        const float* __restrict__ b2, const float* __restrict__ g2,
        const float* __restrict__ be2, const float* __restrict__ w3,
        const float* __restrict__ b3, const int2* __restrict__ etab,
        const float2* __restrict__ statsA, const float2* __restrict__ statsB,
        const float* __restrict__ P, float* __restrict__ out)
{
    extern __shared__ unsigned char smem[];   // 65536 B
    const int tid = threadIdx.x;
    const int w = tid >> 6;            // wave 0..7
    const int l = tid & 63;
    const int b  = blockIdx.x / 510;
    const int eb = blockIdx.x % 510;

    // ---- Phase A: g = gelu(LN1(A_i + B_j)) -> fp16 LDS in MFMA-fragment order.
    // lane: edge e = 8w + (l>>3); k-octets kg = (l&7) + 8t, t=0..7.
    {
        const int el = l >> 3;
        const int kq = l & 7;
        const int e  = w * 8 + el;
        int2 ij = etab[eb * 64 + e];
        float2 sa = statsA[b * 256 + ij.x];
        float2 sb = statsB[b * 256 + ij.y];
        float pij = P[((size_t)b << 16) + ((size_t)ij.x << 8) + ij.y];
        float mean = (sa.x + sb.x) * (1.0f / 512.0f);
        float ex2  = (sa.y + sb.y + 2.0f * pij) * (1.0f / 512.0f);
        float rstd = rsqrtf(ex2 - mean * mean + 1e-5f);
        const float* ar = Am + (((size_t)(b * 256 + ij.x)) << 9);
        const float* br = Bm + (((size_t)(b * 256 + ij.y)) << 9);
        #pragma unroll
        for (int t = 0; t < 8; ++t) {
            const int kg = kq + 8 * t;
            const int k0 = kg * 8;
            f32x4 a0 = *(const f32x4*)(ar + k0);
            f32x4 a1 = *(const f32x4*)(ar + k0 + 4);
            f32x4 c0 = *(const f32x4*)(br + k0);
            f32x4 c1 = *(const f32x4*)(br + k0 + 4);
            f32x4 ga = *(const f32x4*)(g1 + k0);
            f32x4 gb = *(const f32x4*)(g1 + k0 + 4);
            f32x4 ea = *(const f32x4*)(be1 + k0);
            f32x4 ebv= *(const f32x4*)(be1 + k0 + 4);
            half8 hv;
            #pragma unroll
            for (int c = 0; c < 4; ++c) {
                float xa = ((a0[c] + c0[c]) - mean) * rstd * ga[c] + ea[c];
                float xb = ((a1[c] + c1[c]) - mean) * rstd * gb[c] + ebv[c];
                hv[c]     = (_Float16)gelu_f(xa);
                hv[c + 4] = (_Float16)gelu_f(xb);
            }
            *(half8*)(smem + kg * 1024 + ((e ^ (kg & 7)) << 4)) = hv;
        }
    }
    __syncthreads();

    // ---- Phase B: acc[mi][ni] over 4 m-tiles (all 64 edges) x 2 n-tiles (own 32 cols)
    f32x4 acc[4][2] = {};
    const int lg = l >> 4, lr = l & 15;
    const int col0 = w * 32;
    #pragma unroll
    for (int kk = 0; kk < 16; ++kk) {
        const int kg = kk * 4 + lg;
        half8 bf[2];
        #pragma unroll
        for (int ni = 0; ni < 2; ++ni)
            bf[ni] = *(const half8*)(w2f + ((size_t)kg * 256 + col0 + ni * 16 + lr) * 8);
        half8 af[4];
        #pragma unroll
        for (int mi = 0; mi < 4; ++mi)
            af[mi] = *(const half8*)(smem + kg * 1024 + (((mi * 16 + lr) ^ (kg & 7)) << 4));
        #pragma unroll
        for (int mi = 0; mi < 4; ++mi)
            #pragma unroll
            for (int ni = 0; ni < 2; ++ni)
                acc[mi][ni] = __builtin_amdgcn_mfma_f32_16x16x32_f16(af[mi], bf[ni], acc[mi][ni], 0, 0, 0);
    }
    __syncthreads();

    // ---- h2 (+b2) -> LDS as [64 edges][256 cols] f32 (buffer reuse)
    #pragma unroll
    for (int ni = 0; ni < 2; ++ni) {
        const int col = col0 + ni * 16 + lr;
        const float bb = b2[col];
        #pragma unroll
        for (int mi = 0; mi < 4; ++mi)
            #pragma unroll
            for (int r = 0; r < 4; ++r) {
                const int e = mi * 16 + lg * 4 + r;
                *(float*)(smem + e * 1024 + col * 4) = acc[mi][ni][r] + bb;
            }
    }
    __syncthreads();

    // ---- Phase C: LN2 + gelu + dot(w3) + sigmoid (wave w: edges 8w..8w+7)
    {
        const int o0 = l * 4;
        f32x4 g2v = *(const f32x4*)(g2 + o0);
        f32x4 e2v = *(const f32x4*)(be2 + o0);
        f32x4 w3v = *(const f32x4*)(w3 + o0);
        float b3s = b3[0];
        #pragma unroll
        for (int el = 0; el < 8; ++el) {
            const int e = w * 8 + el;
            f32x4 h = *(const f32x4*)(smem + e * 1024 + o0 * 4);
            float s  = h[0] + h[1] + h[2] + h[3];
            float sq = h[0]*h[0] + h[1]*h[1] + h[2]*h[2] + h[3]*h[3];
            s = wred_add(s); sq = wred_add(sq);
            float mean = s * (1.0f / 256.0f);
            float rstd = rsqrtf(sq * (1.0f / 256.0f) - mean * mean + 1e-5f);
            float part = 0.0f;
            #pragma unroll
            for (int c = 0; c < 4; ++c) {
                float xx = (h[c] - mean) * rstd * g2v[c] + e2v[c];
                part += gelu_f(xx) * w3v[c];
            }
            part = wred_add(part);
            if (l == 0)
                out[(size_t)b * E_ + eb * 64 + e] = 1.0f / (1.0f + __expf(-(part + b3s)));
        }
    }
}

// ---------------------------------------------------------------- launch
extern "C" void kernel_launch(void* const* d_in, const int* in_sizes, int n_in,
                              void* d_out, int out_size, void* d_ws, size_t ws_size,
                              hipStream_t stream) {
    const float* verts = (const float*)d_in[0];
    const float* wp    = (const float*)d_in[1];
    const float* bp    = (const float*)d_in[2];
    const float* in_w  = (const float*)d_in[3];
    const float* in_b  = (const float*)d_in[4];
    const float* out_w = (const float*)d_in[5];
    const float* out_b = (const float*)d_in[6];
    const float* w1    = (const float*)d_in[7];
    const float* b1    = (const float*)d_in[8];
    const float* g1    = (const float*)d_in[9];
    const float* be1   = (const float*)d_in[10];
    const float* w2    = (const float*)d_in[11];
    const float* b2    = (const float*)d_in[12];
    const float* g2    = (const float*)d_in[13];
    const float* be2   = (const float*)d_in[14];
    const float* w3    = (const float*)d_in[15];
    const float* b3    = (const float*)d_in[16];
    float* out = (float*)d_out;

    const size_t MB = 1 << 20;
    char* W = (char*)d_ws;
    float*    x     = (float*)(W + 0);                 // 2MB
    _Float16* xhi   = (_Float16*)(W + 2*MB);           // 1MB
    _Float16* xlo   = (_Float16*)(W + 3*MB);           // 1MB
    float*    qkv   = (float*)(W + 4*MB);              // 6MB (dead after attn)
    float*    Amat  = (float*)(W + 4*MB);              // 2MB  (reuse qkv)
    float*    Bmat  = (float*)(W + 6*MB);              // 2MB
    _Float16* Ah    = (_Float16*)(W + 8*MB);           // 1MB
    _Float16* Bh    = (_Float16*)(W + 9*MB);           // 1MB
    _Float16* ctxhi = (_Float16*)(W + 10*MB);          // 1MB
    _Float16* ctxlo = (_Float16*)(W + 11*MB);          // 1MB
    _Float16* w2f   = (_Float16*)(W + 12*MB);          // 256KB (fragment-major)
    int2*     etab  = (int2*)(W + 12*MB + 256*1024);   // 256KB
    float2*   statsA= (float2*)(W + 12*MB + 512*1024); // 8KB
    float2*   statsB= (float2*)(W + 12*MB + 520*1024); // 8KB
    _Float16* iwhi  = (_Float16*)(W + 13*MB);          // 1.5MB
    _Float16* iwlo  = (_Float16*)(W + 13*MB + 1536*1024);
    _Float16* owhi  = (_Float16*)(W + 16*MB);          // 0.5MB
    _Float16* owlo  = (_Float16*)(W + 16*MB + 512*1024);
    _Float16* w1hi  = (_Float16*)(W + 17*MB);          // 1MB
    _Float16* w1lo  = (_Float16*)(W + 18*MB);          // 1MB
    float*    P     = (float*)(W + 19*MB);             // 1MB

    k_vproj<<<dim3(2048), dim3(256), 0, stream>>>(verts, wp, bp, x, xhi, xlo);
    k_prep <<<dim3(6784), dim3(256), 0, stream>>>(w2, w2f, etab, in_w, iwhi, iwlo,
                                                  out_w, owhi, owlo, w1, w1hi, w1lo);
    // qkv = x @ in_w^T + in_b
    k_gemm_sp<0><<<dim3(24, 16), dim3(256), 0, stream>>>(xhi, xlo, iwhi, iwlo, in_b, nullptr,
                                                         qkv, nullptr, nullptr, nullptr, nullptr, 1536);
    k_attn<<<dim3(256), dim3(256), 0, stream>>>(qkv, ctxhi, ctxlo);
    // x = x + ctx @ out_w^T + out_b (in place) ; also refresh xhi/xlo
    k_gemm_sp<1><<<dim3(8, 16), dim3(256), 0, stream>>>(ctxhi, ctxlo, owhi, owlo, out_b, x,
                                                        x, xhi, xlo, nullptr, nullptr, 512);
    // Amat = x @ w1[:, :512]^T + b1 ; Bmat = x @ w1[:, 512:]^T  (+ fp16 copies)
    k_gemm_sp<2><<<dim3(16, 16), dim3(256), 0, stream>>>(xhi, xlo, w1hi, w1lo, b1, nullptr,
                                                         Amat, Ah, nullptr, Bmat, Bh, 512);
    k_rowstats<<<dim3(512), dim3(256), 0, stream>>>(Amat, Bmat, statsA, statsB);
    k_pair<<<dim3(256), dim3(256), 0, stream>>>(Ah, Bh, P);
    k_edge<<<dim3(B_ * 510), dim3(512), 65536, stream>>>(Amat, Bmat, w2f,
                                                         g1, be1, b2, g2, be2, w3, b3,
                                                         etab, statsA, statsB, P, out);
}